// Round 3
// baseline (207.934 us; speedup 1.0000x reference)
//
#include <hip/hip_runtime.h>
#include <stdint.h>

#define NROWS 2048
#define DDIM  9216
#define T64   32                      // max 64-row tiles per dim (2048/64)
#define NTRI  528                     // T64*(T64+1)/2 triangle tiles
#define WKLEN 2304                    // DDIM/4 : K-range per wave
#define BK    32
#define WKIT  72                      // WKLEN/BK : K iterations per wave

typedef unsigned short u16;
typedef __bf16 bf16x8 __attribute__((ext_vector_type(8)));
typedef float  f32x4  __attribute__((ext_vector_type(4)));

// ws layout: [0] int cnt, [4] float sq, [8] int done, [256..) u16 nf[2048][9216]
#define NF_OFF 256

__device__ __forceinline__ u16 f2bf(float f) {
    uint32_t x = __float_as_uint(f);
    x += 0x7fffu + ((x >> 16) & 1u);          // round-to-nearest-even
    return (u16)(x >> 16);
}

__device__ __forceinline__ void gload16(const u16* g, u16* l) {
    __builtin_amdgcn_global_load_lds(
        (const __attribute__((address_space(1))) uint32_t*)g,
        (__attribute__((address_space(3))) uint32_t*)l, 16, 0, 0);
}

// ---------------- kernel 1: per-row stats + normalize + compact ----------------
__global__ __launch_bounds__(256) void stats_kernel(const float* __restrict__ wgt,
                                                    const float* __restrict__ mask,
                                                    u16* __restrict__ nf,
                                                    int* __restrict__ cnt) {
    int n = blockIdx.x;
    if (mask[n] == 0.0f) return;
    int tid = threadIdx.x;
    const float4* row = (const float4*)(wgt + (size_t)n * DDIM);
    float4 v[9];
    float s = 0.f, ss = 0.f;
#pragma unroll
    for (int i = 0; i < 9; ++i) {
        v[i] = row[tid + 256 * i];
        s  += v[i].x + v[i].y + v[i].z + v[i].w;
        ss += v[i].x * v[i].x + v[i].y * v[i].y + v[i].z * v[i].z + v[i].w * v[i].w;
    }
#pragma unroll
    for (int o = 32; o > 0; o >>= 1) { s += __shfl_down(s, o); ss += __shfl_down(ss, o); }
    __shared__ float rs[4], rss[4];
    __shared__ float smean, sinv;
    __shared__ int   sidx;
    int w = tid >> 6, l = tid & 63;
    if (l == 0) { rs[w] = s; rss[w] = ss; }
    __syncthreads();
    if (tid == 0) {
        float S  = rs[0] + rs[1] + rs[2] + rs[3];
        float SS = rss[0] + rss[1] + rss[2] + rss[3];
        float mean = S / (float)DDIM;
        float var  = SS / (float)DDIM - mean * mean;
        float sd   = sqrtf(fmaxf(var, 0.f));
        if (sd == 0.f) sd = 1.f;
        smean = mean; sinv = 1.f / sd;
        sidx = atomicAdd(cnt, 1);
    }
    __syncthreads();
    float mean = smean, inv = sinv;
    u16* dst = nf + (size_t)sidx * DDIM;
#pragma unroll
    for (int i = 0; i < 9; ++i) {
        int e = (tid + 256 * i) * 4;
        uint32_t lo = (uint32_t)f2bf((v[i].x - mean) * inv) |
                      ((uint32_t)f2bf((v[i].y - mean) * inv) << 16);
        uint32_t hi = (uint32_t)f2bf((v[i].z - mean) * inv) |
                      ((uint32_t)f2bf((v[i].w - mean) * inv) << 16);
        uint2 u; u.x = lo; u.y = hi;
        *(uint2*)(dst + e) = u;
    }
}

// ---------------- kernel 2: fused GEMM + square-reduce + finalize ----------------
// 64x64 tile, 4 waves, each wave owns K/4 with PRIVATE double-buffered LDS:
// issue iter+1's 8 global_load_lds, wait vmcnt(8) (current buffer done), compute.
// No __syncthreads in the K-loop. LDS layout XOR-swizzled via the per-lane
// GLOBAL address freedom of global_load_lds -> 2-way banks on ds_read_b128.
template<bool DIAG>
__device__ __forceinline__ void kloop(const u16* pA, const u16* pB,
                                      u16* A0, u16* A1, u16* B0, u16* B1,
                                      int m16, int quad, f32x4 acc[4][4]) {
#define ISSUE(it, bufA, bufB)                                              \
    {                                                                      \
        const u16* a_ = pA + (it) * BK;                                    \
        _Pragma("unroll")                                                  \
        for (int i_ = 0; i_ < 4; ++i_) gload16(a_ + i_ * 16 * DDIM, (bufA) + i_ * 512); \
        if (!DIAG) {                                                       \
            const u16* b_ = pB + (it) * BK;                                \
            _Pragma("unroll")                                              \
            for (int i_ = 0; i_ < 4; ++i_) gload16(b_ + i_ * 16 * DDIM, (bufB) + i_ * 512); \
        }                                                                  \
    }
    ISSUE(0, A0, B0)
    for (int it = 0; it < WKIT; ++it) {
        u16* cA = (it & 1) ? A1 : A0;
        u16* cB = (it & 1) ? B1 : B0;
        if (it != WKIT - 1) {
            u16* nA = (it & 1) ? A0 : A1;
            u16* nB = (it & 1) ? B0 : B1;
            ISSUE(it + 1, nA, nB)
            __builtin_amdgcn_s_waitcnt(DIAG ? 0x0F74 : 0x0F78); // vmcnt(4/8)
        } else {
            __builtin_amdgcn_s_waitcnt(0x0F70);                 // vmcnt(0)
        }
        __builtin_amdgcn_wave_barrier();   // keep ds_reads below the waitcnt
        const u16* rB = DIAG ? cA : cB;
        bf16x8 af[4], bf[4];
#pragma unroll
        for (int fm = 0; fm < 4; ++fm)
            af[fm] = *(const bf16x8*)&cA[fm * 512 + m16 * 32 + ((quad ^ (m16 >> 2)) & 3) * 8];
#pragma unroll
        for (int fn = 0; fn < 4; ++fn)
            bf[fn] = *(const bf16x8*)&rB[fn * 512 + m16 * 32 + ((quad ^ (m16 >> 2)) & 3) * 8];
#pragma unroll
        for (int fm = 0; fm < 4; ++fm)
#pragma unroll
            for (int fn = 0; fn < 4; ++fn) {
                if (DIAG && fm > fn) continue;   // strictly-lower frag blocks unused
                acc[fm][fn] = __builtin_amdgcn_mfma_f32_16x16x32_bf16(
                    af[fm], bf[fn], acc[fm][fn], 0, 0, 0);
            }
    }
#undef ISSUE
}

__global__ __launch_bounds__(256) void gemm_kernel(const u16* __restrict__ nf,
                                                   const int* __restrict__ cnt,
                                                   float* __restrict__ sq,
                                                   int* __restrict__ done,
                                                   float* __restrict__ out) {
    __shared__ u16 ls[32768];                 // 64 KB: 4 waves x 16 KB (A0,A1,B0,B1)
    int A = *cnt;
    int nt = (A + 63) >> 6;
    int t = blockIdx.x, bi = 0, len = T64;
    while (t >= len) { t -= len; --len; ++bi; }
    int bj = bi + t;
    bool active = (bj < nt);                  // block-uniform
    int tid = threadIdx.x, l = tid & 63, w = tid >> 6;

    if (active) {
        int r0 = bi << 6, c0 = bj << 6;
        int quad = l >> 4, m16 = l & 15;
        // per-lane global mapping (XOR swizzle): row = l>>2, kgroup = (l&3)^((l>>4)&3)
        int rowoff = l >> 2;
        int qg = (l & 3) ^ ((l >> 4) & 3);
        int kbeg = w * WKLEN;
        const u16* pA = nf + (size_t)(r0 + rowoff) * DDIM + kbeg + qg * 8;
        const u16* pB = nf + (size_t)(c0 + rowoff) * DDIM + kbeg + qg * 8;
        u16* base = ls + w * 8192;            // 16 KB per wave
        u16 *A0 = base, *A1 = base + 2048, *B0 = base + 4096, *B1 = base + 6144;
        f32x4 acc[4][4] = {};
        if (bi == bj) kloop<true >(pA, pB, A0, A1, B0, B1, m16, quad, acc);
        else          kloop<false>(pA, pB, A0, A1, B0, B1, m16, quad, acc);

        // park partials in own wave's LDS region (overlays own bufs)
        float* fw = (float*)ls + w * 4096;
#pragma unroll
        for (int fm = 0; fm < 4; ++fm)
#pragma unroll
            for (int fn = 0; fn < 4; ++fn)
                *(f32x4*)&fw[(fm * 4 + fn) * 256 + l * 4] = acc[fm][fn];
        __syncthreads();
        const float* fs = (const float*)ls;
        float local = 0.f;
#pragma unroll
        for (int i = 0; i < 4; ++i) {
            int o = tid * 4 + i * 1024;
            f32x4 v = *(const f32x4*)&fs[o];
            v += *(const f32x4*)&fs[o + 4096];
            v += *(const f32x4*)&fs[o + 8192];
            v += *(const f32x4*)&fs[o + 12288];
            int f = o >> 8, lk = (o >> 2) & 63;
            int row = ((f >> 2) << 4) + ((lk >> 4) << 2);
            int col = ((f & 3) << 4) + (lk & 15);
            int gj = c0 + col;
            if (gj < A) {
#pragma unroll
                for (int r = 0; r < 4; ++r) {
                    int gi = r0 + row + r;
                    if (gi < gj) local += v[r] * v[r];
                }
            }
        }
#pragma unroll
        for (int o = 32; o > 0; o >>= 1) local += __shfl_down(local, o);
        if (l == 0) atomicAdd(sq, local);
    }
    __syncthreads();                          // all waves' sq atomics issued & drained
    if (tid == 0) {
        __threadfence();                      // order sq adds before done increment
        int old = atomicAdd(done, 1);
        if (old == (int)gridDim.x - 1) {      // last block finalizes
            float s = atomicAdd(sq, 0.0f);    // device-coherent read
            long long AA = A;
            long long na = AA * (AA - 1) / 2;
            double loss = 0.0;
            if (na > 0) loss = (double)s / ((double)DDIM * (double)DDIM) / (double)na;
            out[0] = (float)loss;
        }
    }
}

extern "C" void kernel_launch(void* const* d_in, const int* in_sizes, int n_in,
                              void* d_out, int out_size, void* d_ws, size_t ws_size,
                              hipStream_t stream) {
    (void)in_sizes; (void)n_in; (void)out_size; (void)ws_size;
    const float* wgt  = (const float*)d_in[0];
    const float* mask = (const float*)d_in[1];
    float* out = (float*)d_out;
    char*  ws  = (char*)d_ws;

    int*   cnt  = (int*)ws;
    float* sq   = (float*)(ws + 4);
    int*   done = (int*)(ws + 8);
    u16*   nf   = (u16*)(ws + NF_OFF);

    hipMemsetAsync(ws, 0, 256, stream);
    stats_kernel<<<NROWS, 256, 0, stream>>>(wgt, mask, nf, cnt);
    gemm_kernel<<<NTRI, 256, 0, stream>>>(nf, cnt, sq, done, out);
}

// Round 4
// 176.712 us; speedup vs baseline: 1.1767x; 1.1767x over previous
//
#include <hip/hip_runtime.h>
#include <stdint.h>

#define NROWS 2048
#define DDIM  9216
#define T64   32                      // max 64-row tiles per dim (2048/64)
#define NTRI  528                     // T64*(T64+1)/2 triangle tiles
#define WKLEN 1152                    // DDIM/8 : K-range per wave (8 waves)
#define BK    64                      // 128 B per row per iter (full cache lines)
#define WKIT  18                      // WKLEN/BK

typedef unsigned short u16;
typedef __bf16 bf16x8 __attribute__((ext_vector_type(8)));
typedef float  f32x4  __attribute__((ext_vector_type(4)));

// ws layout: [0] int cnt, [4] float sq, [8] int done, [256..) u16 nf[2048][9216]
#define NF_OFF 256

__device__ __forceinline__ u16 f2bf(float f) {
    uint32_t x = __float_as_uint(f);
    x += 0x7fffu + ((x >> 16) & 1u);          // round-to-nearest-even
    return (u16)(x >> 16);
}

__device__ __forceinline__ void gload16(const u16* g, u16* l) {
    __builtin_amdgcn_global_load_lds(
        (const __attribute__((address_space(1))) uint32_t*)g,
        (__attribute__((address_space(3))) uint32_t*)l, 16, 0, 0);
}

// ---------------- kernel 1: per-row stats + normalize + compact ----------------
__global__ __launch_bounds__(256) void stats_kernel(const float* __restrict__ wgt,
                                                    const float* __restrict__ mask,
                                                    u16* __restrict__ nf,
                                                    int* __restrict__ cnt) {
    int n = blockIdx.x;
    if (mask[n] == 0.0f) return;
    int tid = threadIdx.x;
    const float4* row = (const float4*)(wgt + (size_t)n * DDIM);
    float4 v[9];
    float s = 0.f, ss = 0.f;
#pragma unroll
    for (int i = 0; i < 9; ++i) {
        v[i] = row[tid + 256 * i];
        s  += v[i].x + v[i].y + v[i].z + v[i].w;
        ss += v[i].x * v[i].x + v[i].y * v[i].y + v[i].z * v[i].z + v[i].w * v[i].w;
    }
#pragma unroll
    for (int o = 32; o > 0; o >>= 1) { s += __shfl_down(s, o); ss += __shfl_down(ss, o); }
    __shared__ float rs[4], rss[4];
    __shared__ float smean, sinv;
    __shared__ int   sidx;
    int w = tid >> 6, l = tid & 63;
    if (l == 0) { rs[w] = s; rss[w] = ss; }
    __syncthreads();
    if (tid == 0) {
        float S  = rs[0] + rs[1] + rs[2] + rs[3];
        float SS = rss[0] + rss[1] + rss[2] + rss[3];
        float mean = S / (float)DDIM;
        float var  = SS / (float)DDIM - mean * mean;
        float sd   = sqrtf(fmaxf(var, 0.f));
        if (sd == 0.f) sd = 1.f;
        smean = mean; sinv = 1.f / sd;
        sidx = atomicAdd(cnt, 1);
    }
    __syncthreads();
    float mean = smean, inv = sinv;
    u16* dst = nf + (size_t)sidx * DDIM;
#pragma unroll
    for (int i = 0; i < 9; ++i) {
        int e = (tid + 256 * i) * 4;
        uint32_t lo = (uint32_t)f2bf((v[i].x - mean) * inv) |
                      ((uint32_t)f2bf((v[i].y - mean) * inv) << 16);
        uint32_t hi = (uint32_t)f2bf((v[i].z - mean) * inv) |
                      ((uint32_t)f2bf((v[i].w - mean) * inv) << 16);
        uint2 u; u.x = lo; u.y = hi;
        *(uint2*)(dst + e) = u;
    }
}

// ---------------- kernel 2: fused GEMM + square-reduce + finalize ----------------
// 64x64 tile, 8 waves, each wave owns K/8=1152 with PRIVATE single-buffered LDS
// (A 8KB + B 8KB), BK=64 => every row load is one full 128 B cache line.
// vmcnt(0) drain per iter (compiler inserts it anyway); latency hidden by
// 2 waves/SIMD TLP. LDS XOR-swizzled: row r stores 16B chunk c at slot c^(r&7),
// realized for free via the per-lane GLOBAL address of global_load_lds.
template<bool DIAG>
__device__ __forceinline__ void kloop(const u16* pA, const u16* pB,
                                      u16* bufA, u16* bufB,
                                      int m16, int quad, f32x4 acc[4][4]) {
    int sw = m16 & 7;                         // row-dependent swizzle key
    for (int it = 0; it < WKIT; ++it) {
        const u16* a_ = pA + it * BK;
#pragma unroll
        for (int i = 0; i < 8; ++i) gload16(a_ + i * 8 * DDIM, bufA + i * 512);
        if (!DIAG) {
            const u16* b_ = pB + it * BK;
#pragma unroll
            for (int i = 0; i < 8; ++i) gload16(b_ + i * 8 * DDIM, bufB + i * 512);
        }
        __builtin_amdgcn_s_waitcnt(0x0F70);   // vmcnt(0)
        __builtin_amdgcn_wave_barrier();
        const u16* rB = DIAG ? bufA : bufB;
#pragma unroll
        for (int kk = 0; kk < 2; ++kk) {
            int slot8 = ((kk * 4 + quad) ^ sw) * 8;
            bf16x8 af[4], bf[4];
#pragma unroll
            for (int fm = 0; fm < 4; ++fm)
                af[fm] = *(const bf16x8*)&bufA[(fm * 16 + m16) * BK + slot8];
#pragma unroll
            for (int fn = 0; fn < 4; ++fn)
                bf[fn] = *(const bf16x8*)&rB[(fn * 16 + m16) * BK + slot8];
#pragma unroll
            for (int fm = 0; fm < 4; ++fm)
#pragma unroll
                for (int fn = 0; fn < 4; ++fn) {
                    if (DIAG && fm > fn) continue;
                    acc[fm][fn] = __builtin_amdgcn_mfma_f32_16x16x32_bf16(
                        af[fm], bf[fn], acc[fm][fn], 0, 0, 0);
                }
        }
        __builtin_amdgcn_wave_barrier();      // next iter's DMA after this iter's reads
    }
}

__global__ __launch_bounds__(512, 2) void gemm_kernel(const u16* __restrict__ nf,
                                                      const int* __restrict__ cnt,
                                                      float* __restrict__ sq,
                                                      int* __restrict__ done,
                                                      float* __restrict__ out) {
    __shared__ u16 ls[65536];                 // 128 KB: 8 waves x (A 8KB + B 8KB)
    int A = *cnt;
    int nt = (A + 63) >> 6;
    int t = blockIdx.x, bi = 0, len = T64;
    while (t >= len) { t -= len; --len; ++bi; }
    int bj = bi + t;
    bool active = (bj < nt);                  // block-uniform
    int tid = threadIdx.x, l = tid & 63, w = tid >> 6;
    int r0 = bi << 6, c0 = bj << 6;

    if (active) {
        int quad = l >> 4, m16 = l & 15;
        // staging: lane l covers row (l>>3), chunk slot (l&7); global chunk = slot ^ row
        int srow = l >> 3;
        int c    = (l & 7) ^ srow;
        int kbeg = w * WKLEN;
        const u16* pA = nf + (size_t)(r0 + srow) * DDIM + kbeg + c * 8;
        const u16* pB = nf + (size_t)(c0 + srow) * DDIM + kbeg + c * 8;
        u16* bufA = ls + w * 8192;            // 16 KB per wave
        u16* bufB = bufA + 4096;
        f32x4 acc[4][4] = {};
        if (bi == bj) kloop<true >(pA, pB, bufA, bufB, m16, quad, acc);
        else          kloop<false>(pA, pB, bufA, bufB, m16, quad, acc);

        // ---- park all 8 partial 64x64 tiles in LDS (8 x 16 KB = 128 KB) ----
        float* fw = (float*)ls + w * 4096;
#pragma unroll
        for (int fm = 0; fm < 4; ++fm)
#pragma unroll
            for (int fn = 0; fn < 4; ++fn)
                *(f32x4*)&fw[(fm * 4 + fn) * 256 + l * 4] = acc[fm][fn];
        __syncthreads();
        const float* fs = (const float*)ls;
        float local = 0.f;
#pragma unroll
        for (int j = 0; j < 2; ++j) {
            int o = tid * 8 + j * 4;          // element offset within a wave slice
            f32x4 v = *(const f32x4*)&fs[o];
#pragma unroll
            for (int ww = 1; ww < 8; ++ww) v += *(const f32x4*)&fs[o + ww * 4096];
            int f = o >> 8, lk = (o >> 2) & 63;
            int row = ((f >> 2) << 4) + ((lk >> 4) << 2);
            int col = ((f & 3) << 4) + (lk & 15);
            int gj = c0 + col;
            if (gj < A) {
#pragma unroll
                for (int r = 0; r < 4; ++r) {
                    int gi = r0 + row + r;
                    if (gi < gj) local += v[r] * v[r];
                }
            }
        }
#pragma unroll
        for (int o = 32; o > 0; o >>= 1) local += __shfl_down(local, o);
        if (l == 0) atomicAdd(sq, local);
    }
    __syncthreads();
    if (tid == 0) {
        __threadfence();
        int old = atomicAdd(done, 1);
        if (old == (int)gridDim.x - 1) {      // last block finalizes
            float s = atomicAdd(sq, 0.0f);    // device-coherent read
            long long AA = A;
            long long na = AA * (AA - 1) / 2;
            double loss = 0.0;
            if (na > 0) loss = (double)s / ((double)DDIM * (double)DDIM) / (double)na;
            out[0] = (float)loss;
        }
    }
}

extern "C" void kernel_launch(void* const* d_in, const int* in_sizes, int n_in,
                              void* d_out, int out_size, void* d_ws, size_t ws_size,
                              hipStream_t stream) {
    (void)in_sizes; (void)n_in; (void)out_size; (void)ws_size;
    const float* wgt  = (const float*)d_in[0];
    const float* mask = (const float*)d_in[1];
    float* out = (float*)d_out;
    char*  ws  = (char*)d_ws;

    int*   cnt  = (int*)ws;
    float* sq   = (float*)(ws + 4);
    int*   done = (int*)(ws + 8);
    u16*   nf   = (u16*)(ws + NF_OFF);

    hipMemsetAsync(ws, 0, 256, stream);
    stats_kernel<<<NROWS, 256, 0, stream>>>(wgt, mask, nf, cnt);
    gemm_kernel<<<NTRI, 512, 0, stream>>>(nf, cnt, sq, done, out);
}